// Round 9
// baseline (114.920 us; speedup 1.0000x reference)
//
#include <hip/hip_runtime.h>
#include <hip/hip_bf16.h>
#include <math.h>

// Problem constants (static config in reference)
#define NT      4096              // B*T
#define DD      1024              // D
#define EE      8                 // experts
#define KK      2                 // top-k
#define CAP     1280              // EXP_CAP
#define CBN     (NT * EE * CAP)   // 41,943,040 elements per big output

#define NB      256               // blocks (1 per CU)
#define BT      1024              // threads per block (16 waves)
#define WPB     (BT / 64)         // 16 waves/block
#define NWAVE   (NB * WPB)        // 4096 waves == NT (1 token per wave)
#define F4TOT   (2 * CBN / 4)     // 20,971,520 float4 to zero (out[8..])
#define F4PW    (F4TOT / NWAVE)   // 5120 float4 per wave (80 per lane)
#define JPT     (KK * NT / BT)    // 8 assignments per thread (phase 2)

typedef float vf4 __attribute__((ext_vector_type(4)));

// LDS index swizzle (involution): spreads per-thread contiguous walks
// across banks.
__device__ __forceinline__ int swz(int j) { return j ^ ((j >> 5) & 31); }

// ---------------------------------------------------------------------------
// All-in-one kernel:
//   phase 1 (all 256 blocks): logits/top2/softmax (1 token/wave) + nt-store
//     zero-fill of a contiguous 80KB slice per wave (tests the 7 TB/s theory).
//   arrival: atomicAdd; the LAST block to arrive (all fills + logits released)
//     runs phase 2: ordered rank / capacity / used_cap / scatter.
// ---------------------------------------------------------------------------
__global__ __launch_bounds__(BT) void fused_all_kernel(
    const float* __restrict__ x,        // (NT, D)
    const float* __restrict__ w,        // (E, D)
    float* __restrict__ out,
    unsigned* __restrict__ cnt,
    int* __restrict__ e0, int* __restrict__ e1,
    float* __restrict__ p0, float* __restrict__ p1)
{
    __shared__ union {
        float wl[EE * DD];                              // 32 KB (phase 1)
        struct { int se[KK * NT]; float sp[KK * NT]; } s2;  // 64 KB (phase 2)
    } u;
    __shared__ unsigned long long wsumA[WPB], wsumB[WPB];
    __shared__ int lastflag;

    const int tid  = threadIdx.x;
    const int wave = tid >> 6;
    const int lane = tid & 63;

    // ---------------- Phase 1a: logits + top-2 + softmax (1 token/wave) ----
    for (int i = tid; i < EE * DD / 4; i += BT)
        reinterpret_cast<float4*>(u.wl)[i] = reinterpret_cast<const float4*>(w)[i];
    __syncthreads();

    const int t = blockIdx.x * WPB + wave;              // 0..4095
    {
        const float4* xt = reinterpret_cast<const float4*>(x + (size_t)t * DD);
        float acc[EE];
        #pragma unroll
        for (int e = 0; e < EE; ++e) acc[e] = 0.0f;

        #pragma unroll
        for (int ii = 0; ii < DD / 4 / 64; ++ii) {      // 4 iters
            const int i = ii * 64 + lane;
            const float4 xv = xt[i];
            #pragma unroll
            for (int e = 0; e < EE; ++e) {
                const float4 wv = reinterpret_cast<const float4*>(u.wl + e * DD)[i];
                acc[e] += xv.x * wv.x + xv.y * wv.y + xv.z * wv.z + xv.w * wv.w;
            }
        }

        #pragma unroll
        for (int e = 0; e < EE; ++e) {
            float v = acc[e];
            #pragma unroll
            for (int off = 32; off > 0; off >>= 1) v += __shfl_xor(v, off);
            acc[e] = v;
        }

        if (lane == 0) {
            int b0 = 0; float l0 = acc[0];
            #pragma unroll
            for (int e = 1; e < EE; ++e) { if (acc[e] > l0) { l0 = acc[e]; b0 = e; } }
            int b1 = -1; float l1 = -INFINITY;
            #pragma unroll
            for (int e = 0; e < EE; ++e) { if (e != b0 && acc[e] > l1) { l1 = acc[e]; b1 = e; } }

            const float z  = expf(l1 - l0);             // l1 <= l0
            const float pa = 1.0f / (1.0f + z);
            const float pb = z * pa;

            e0[t] = b0; e1[t] = b1;
            p0[t] = pa; p1[t] = pb;
        }
    }

    // ---------------- Phase 1b: nt-store zero-fill (80 KB contiguous/wave) --
    {
        const int gw = blockIdx.x * WPB + wave;         // 0..4095
        vf4* dst = reinterpret_cast<vf4*>(out + 8) + (size_t)gw * F4PW + lane;
        const vf4 zv = {0.0f, 0.0f, 0.0f, 0.0f};
        #pragma unroll 8
        for (int it = 0; it < F4PW / 64; ++it)          // 80 nt stores/lane
            __builtin_nontemporal_store(zv, dst + it * 64);
    }

    // ---------------- Arrival: last block runs phase 2 ----------------
    __syncthreads();
    if (tid == 0) {
        const unsigned old = __hip_atomic_fetch_add(cnt, 1u, __ATOMIC_ACQ_REL,
                                                    __HIP_MEMORY_SCOPE_AGENT);
        lastflag = (old == NB - 1);
    }
    __syncthreads();
    if (!lastflag) return;

    // ---------------- Phase 2: ordered rank -> used_cap + scatter ----------
    // (validated round 8: 1024 threads, 8 assignments each)
    #pragma unroll
    for (int k = 0; k < NT / BT; ++k) {                 // 4 iters
        const int i = k * BT + tid;
        u.s2.se[swz(i)]      = e0[i];
        u.s2.se[swz(NT + i)] = e1[i];
        u.s2.sp[swz(i)]      = p0[i];
        u.s2.sp[swz(NT + i)] = p1[i];
    }
    __syncthreads();

    const int base = tid * JPT;
    unsigned long long ca = 0ull, cb = 0ull;            // experts 0-3 / 4-7, 16b fields
    #pragma unroll
    for (int i = 0; i < JPT; ++i) {
        const int e = u.s2.se[swz(base + i)];
        if (e < 4) ca += 1ull << (16 * e);
        else       cb += 1ull << (16 * (e - 4));
    }

    unsigned long long sa = ca, sb = cb;                // intra-wave inclusive scan
    #pragma unroll
    for (int off = 1; off < 64; off <<= 1) {
        const unsigned long long ta = __shfl_up(sa, off);
        const unsigned long long tb = __shfl_up(sb, off);
        if ((tid & 63) >= off) { sa += ta; sb += tb; }
    }
    if ((tid & 63) == 63) { wsumA[wave] = sa; wsumB[wave] = sb; }
    __syncthreads();

    unsigned long long preA = 0ull, preB = 0ull;
    #pragma unroll
    for (int k = 0; k < WPB; ++k) {
        if (k < wave) { preA += wsumA[k]; preB += wsumB[k]; }
    }
    unsigned long long ra = preA + sa - ca;             // exclusive prefix
    unsigned long long rb = preB + sb - cb;

    // replay in ascending j order + scatter into the (already zeroed) output
    #pragma unroll
    for (int i = 0; i < JPT; ++i) {
        const int j = base + i;
        const int e = u.s2.se[swz(j)];
        int rank;
        if (e < 4) { rank = (int)((ra >> (16 * e)) & 0xFFFF);       ra += 1ull << (16 * e); }
        else       { rank = (int)((rb >> (16 * (e - 4))) & 0xFFFF); rb += 1ull << (16 * (e - 4)); }
        if (rank < CAP) {
            const float p = u.s2.sp[swz(j)];
            if (p != 0.0f) {                            // sec_mask == (cb_weight != 0)
                const int tt = j & (NT - 1);
                const size_t idx = (size_t)tt * (EE * CAP) + (size_t)e * CAP + (size_t)rank;
                out[8 + idx] = p;
                out[8 + (size_t)CBN + idx] = 1.0f;
            }
        }
    }

    // used_cap -> out[0..7]
    if (tid < EE) {
        unsigned long long totA = 0ull, totB = 0ull;
        #pragma unroll
        for (int k = 0; k < WPB; ++k) { totA += wsumA[k]; totB += wsumB[k]; }
        const int e = tid;
        const int tot = (e < 4) ? (int)((totA >> (16 * e)) & 0xFFFF)
                                : (int)((totB >> (16 * (e - 4))) & 0xFFFF);
        out[e] = (float)((tot < CAP) ? tot : CAP);
    }
}

// ---------------------------------------------------------------------------
extern "C" void kernel_launch(void* const* d_in, const int* in_sizes, int n_in,
                              void* d_out, int out_size, void* d_ws, size_t ws_size,
                              hipStream_t stream) {
    const float* x = (const float*)d_in[0];     // (B,T,D) f32
    const float* w = (const float*)d_in[1];     // (E,D)   f32
    float* out = (float*)d_out;

    char* ws = (char*)d_ws;
    unsigned* cnt = (unsigned*)(ws);            // 64 B arrival counter
    int*   e0 = (int*)(ws + 1 * 1024);          // 16 KB
    int*   e1 = (int*)(ws + 17 * 1024);         // 16 KB
    float* p0 = (float*)(ws + 33 * 1024);       // 16 KB
    float* p1 = (float*)(ws + 49 * 1024);       // 16 KB

    // zero the arrival counter each replay (tiny node, poison-proof)
    hipMemsetAsync(cnt, 0, 64, stream);

    // one kernel: logits + nt-fill -> last-arriving block ranks & scatters
    fused_all_kernel<<<NB, BT, 0, stream>>>(x, w, out, cnt, e0, e1, p0, p1);
}